// Round 12
// baseline (316.140 us; speedup 1.0000x reference)
//
#include <hip/hip_runtime.h>
#include <hip/hip_fp16.h>
#include <math.h>
#include <stdint.h>

#define NN 50000
#define NE 800000
#define NG 64
#define NEG_SLOPE 0.2f
#define BSH 8
#define NBUCK ((NN + 255) >> 8)   // 196 dst-buckets (256 nodes each)

typedef unsigned short u16;
typedef unsigned char u8;
typedef __attribute__((ext_vector_type(8))) unsigned short ushort8;
typedef __attribute__((ext_vector_type(8))) short short8v;   // MFMA bf16 A/B frag (4 VGPRs)
typedef __attribute__((ext_vector_type(4))) float f32x4;     // MFMA C/D frag

__device__ __forceinline__ float lrelu(float x) { return x > 0.f ? x : NEG_SLOPE * x; }
__device__ __forceinline__ float bf2f(u16 u) { return __uint_as_float(((unsigned)u) << 16); }
__device__ __forceinline__ u16 f2bf(float f) {
    unsigned b = __float_as_uint(f);
    return (u16)((b + 0x7FFF + ((b >> 16) & 1)) >> 16);  // RNE
}

// ---------------- fp8 e4m3 pack/unpack (HW cvt on gfx950; SW fallback self-consistent) ----------------
#if __has_builtin(__builtin_amdgcn_cvt_pk_fp8_f32) && __has_builtin(__builtin_amdgcn_cvt_pk_f32_fp8)
__device__ __forceinline__ uint2 fp8x8_enc(const float* v) {
    int lo = __builtin_amdgcn_cvt_pk_fp8_f32(v[0], v[1], 0, false);
    lo = __builtin_amdgcn_cvt_pk_fp8_f32(v[2], v[3], lo, true);
    int hi = __builtin_amdgcn_cvt_pk_fp8_f32(v[4], v[5], 0, false);
    hi = __builtin_amdgcn_cvt_pk_fp8_f32(v[6], v[7], hi, true);
    uint2 r; r.x = (unsigned)lo; r.y = (unsigned)hi; return r;
}
__device__ __forceinline__ void fp8x8_dec(uint2 hv, float* f) {
    auto a = __builtin_amdgcn_cvt_pk_f32_fp8((int)hv.x, false);
    auto b = __builtin_amdgcn_cvt_pk_f32_fp8((int)hv.x, true);
    auto c = __builtin_amdgcn_cvt_pk_f32_fp8((int)hv.y, false);
    auto d = __builtin_amdgcn_cvt_pk_f32_fp8((int)hv.y, true);
    f[0] = a[0]; f[1] = a[1]; f[2] = b[0]; f[3] = b[1];
    f[4] = c[0]; f[5] = c[1]; f[6] = d[0]; f[7] = d[1];
}
#else
__device__ __forceinline__ u8 f2fp8(float fv) {
    unsigned b = __float_as_uint(fv);
    unsigned s = (b >> 24) & 0x80;
    int e = (b >> 23) & 0xff;
    unsigned m = b & 0x7fffff;
    m += 0x7ffff + ((m >> 20) & 1);           // round
    if (m & 0x800000) { e++; m = 0; }
    int E = e - 120;                           // e4m3 exponent (bias 7)
    unsigned r;
    if (E <= 0) r = 0;                         // flush denormal
    else if (E > 15) r = 0x7e;                 // saturate to 448
    else r = ((unsigned)E << 3) | (m >> 20);
    return (u8)(r | s);
}
__device__ __forceinline__ float fp82f(u8 bb) {
    int t = ((bb & 0x80) << 8) | ((bb & 0x7f) << 7);
    if (bb & 0x78) t += 0x2000;                // exp bias 7 -> 15
    __half_raw hr; hr.x = (unsigned short)t;
    return __half2float(*(__half*)&hr);
}
__device__ __forceinline__ uint2 fp8x8_enc(const float* v) {
    unsigned lo = 0, hi = 0;
    for (int i = 0; i < 4; i++) lo |= ((unsigned)f2fp8(v[i])) << (8 * i);
    for (int i = 0; i < 4; i++) hi |= ((unsigned)f2fp8(v[4 + i])) << (8 * i);
    uint2 r; r.x = lo; r.y = hi; return r;
}
__device__ __forceinline__ void fp8x8_dec(uint2 hv, float* f) {
    for (int i = 0; i < 4; i++) f[i] = fp82f((u8)((hv.x >> (8 * i)) & 0xff));
    for (int i = 0; i < 4; i++) f[4 + i] = fp82f((u8)((hv.y >> (8 * i)) & 0xff));
}
#endif

// ---------------- column stats fp32 input ----------------
__global__ __launch_bounds__(256) void col_stats_kernel(const float* __restrict__ X, int nrows,
                                                        float* __restrict__ sum, float* __restrict__ ssum) {
    int tid = threadIdx.x;
    int c = tid & 127, half = tid >> 7;
    int rows_per = (nrows + gridDim.x - 1) / gridDim.x;
    int r0 = blockIdx.x * rows_per;
    int r1 = r0 + rows_per; if (r1 > nrows) r1 = nrows;
    float s = 0.f, ss = 0.f;
    for (int r = r0 + half; r < r1; r += 2) {
        float v = X[(size_t)r * 128 + c];
        s += v; ss += v * v;
    }
    __shared__ float sm1[256], sm2[256];
    sm1[tid] = s; sm2[tid] = ss;
    __syncthreads();
    if (tid < 128) {
        s = sm1[tid] + sm1[tid + 128];
        ss = sm2[tid] + sm2[tid + 128];
        atomicAdd(&sum[c], s);
        atomicAdd(&ssum[c], ss);
    }
}

// ---------------- column stats bf16 input ----------------
__global__ __launch_bounds__(256) void col_stats_bf16_kernel(const u16* __restrict__ X, int nrows,
                                                             float* __restrict__ sum, float* __restrict__ ssum) {
    int tid = threadIdx.x;
    int c = tid & 127, half = tid >> 7;
    int rows_per = (nrows + gridDim.x - 1) / gridDim.x;
    int r0 = blockIdx.x * rows_per;
    int r1 = r0 + rows_per; if (r1 > nrows) r1 = nrows;
    float s = 0.f, ss = 0.f;
    for (int r = r0 + half; r < r1; r += 2) {
        float v = bf2f(X[(size_t)r * 128 + c]);
        s += v; ss += v * v;
    }
    __shared__ float sm1[256], sm2[256];
    sm1[tid] = s; sm2[tid] = ss;
    __syncthreads();
    if (tid < 128) {
        s = sm1[tid] + sm1[tid + 128];
        ss = sm2[tid] + sm2[tid + 128];
        atomicAdd(&sum[c], s);
        atomicAdd(&ssum[c], ss);
    }
}

// ---------------- BN fold layer1: W1pT[j][k] = bf16(a_k*W[k][j]); hbias fp32 ----------------
__global__ __launch_bounds__(128) void bn_prep1_kernel(const float* __restrict__ sum, const float* __restrict__ ssum,
                                                       const float* __restrict__ gamma, const float* __restrict__ beta,
                                                       const float* __restrict__ W, float inv_n,
                                                       u16* __restrict__ WpT, float* __restrict__ hb) {
    int k = threadIdx.x; // 128
    float mean = sum[k] * inv_n;
    float var = ssum[k] * inv_n - mean * mean;
    float a = gamma[k] * rsqrtf(var + 1e-5f);
    float b = beta[k] - mean * a;
    for (int j = 0; j < 128; j++) WpT[j * 128 + k] = f2bf(a * W[k * 128 + j]);
    __shared__ float bs[128];
    bs[k] = b;
    __syncthreads();
    float acc = 0.f;
    for (int kk = 0; kk < 128; kk++) acc += bs[kk] * W[kk * 128 + k];
    hb[k] = acc;
}

// ---------------- BN fold layer2: W2pT[j][k] (bf16, 16x128) + h2bias ----------------
__global__ __launch_bounds__(128) void bn_prep2_kernel(const float* __restrict__ sum, const float* __restrict__ ssum,
                                                       const float* __restrict__ gamma, const float* __restrict__ beta,
                                                       const float* __restrict__ W, float inv_n,
                                                       u16* __restrict__ WpT, float* __restrict__ hb) {
    int k = threadIdx.x; // 128
    float mean = sum[k] * inv_n;
    float var = ssum[k] * inv_n - mean * mean;
    float a = gamma[k] * rsqrtf(var + 1e-5f);
    float b = beta[k] - mean * a;
    for (int j = 0; j < 16; j++) WpT[j * 128 + k] = f2bf(a * W[k * 16 + j]);
    __shared__ float bs[128];
    bs[k] = b;
    __syncthreads();
    if (k < 16) {
        float acc = 0.f;
        for (int kk = 0; kk < 128; kk++) acc += bs[kk] * W[kk * 16 + k];
        hb[k] = acc;
    }
}

// ---------------- GEMM1 via MFMA bf16 -> fp8 H table + fused as1/ad1 epilogue ----------------
__global__ __launch_bounds__(256) void gemm1_mfma_kernel(const float* __restrict__ X, const u16* __restrict__ WpT,
                                                         const float* __restrict__ hbias, const float* __restrict__ atts,
                                                         const float* __restrict__ attd, u8* __restrict__ H8,
                                                         float* __restrict__ as_o, float* __restrict__ ad_o) {
    __shared__ __align__(16) char smem[34816];   // max(128*136*2, 64*128*4)
    u16 (*wlds)[136] = (u16(*)[136])smem;
    int tid = threadIdx.x;
    for (int u = tid; u < 2048; u += 256) {    // 128 cols x 16 chunks of 8 u16
        int c = u >> 4, ch = u & 15;
        *(ushort8*)&wlds[c][ch * 8] = *(const ushort8*)&WpT[c * 128 + ch * 8];
    }
    int lane = tid & 63;
    int wv = tid >> 6;
    int cl = lane & 15;
    int kg = lane >> 4;
    int row_base = blockIdx.x * 64 + wv * 16;
    int rr = min(row_base + cl, NN - 1);       // A row (clamped; invalid rows discarded at store)

    short8v afrag[4];
#pragma unroll
    for (int kb = 0; kb < 4; kb++) {
        const float* xp = &X[(size_t)rr * 128 + kb * 32 + kg * 8];
        float4 x0 = *(const float4*)xp;
        float4 x1 = *(const float4*)(xp + 4);
        ushort8 t;
        t[0] = f2bf(x0.x); t[1] = f2bf(x0.y); t[2] = f2bf(x0.z); t[3] = f2bf(x0.w);
        t[4] = f2bf(x1.x); t[5] = f2bf(x1.y); t[6] = f2bf(x1.z); t[7] = f2bf(x1.w);
        afrag[kb] = (short8v)t;
    }
    __syncthreads();

    f32x4 acc[8];
#pragma unroll
    for (int ct = 0; ct < 8; ct++) {
        f32x4 a = {0.f, 0.f, 0.f, 0.f};
#pragma unroll
        for (int kb = 0; kb < 4; kb++) {
            ushort8 bv = *(const ushort8*)&wlds[ct * 16 + cl][kb * 32 + kg * 8];
            a = __builtin_amdgcn_mfma_f32_16x16x32_bf16(afrag[kb], (short8v)bv, a, 0, 0, 0);
        }
        acc[ct] = a;
    }

    // as1/ad1 epilogue from registers (per-head dot + 16-lane reduce)
#pragma unroll
    for (int reg = 0; reg < 4; reg++) {
        int r = row_base + kg * 4 + reg;       // C/D row mapping (m89)
        bool valid = (r < NN);
        float sp[4] = {0.f, 0.f, 0.f, 0.f}, dp[4] = {0.f, 0.f, 0.f, 0.f};
#pragma unroll
        for (int ct = 0; ct < 8; ct++) {
            int c = ct * 16 + cl;
            float v = acc[ct][reg] + hbias[c];
            sp[ct >> 1] += v * atts[c];
            dp[ct >> 1] += v * attd[c];
        }
#pragma unroll
        for (int off = 1; off < 16; off <<= 1) {
#pragma unroll
            for (int h = 0; h < 4; h++) {
                sp[h] += __shfl_xor(sp[h], off);
                dp[h] += __shfl_xor(dp[h], off);
            }
        }
        if (valid) {
            if (cl < 4) as_o[r * 4 + cl] = sp[cl];
            else if (cl < 8) ad_o[r * 4 + (cl - 4)] = dp[cl - 4];
        }
    }

    // restage through LDS for coalesced fp8 packing
    __syncthreads();   // all wlds reads complete before overwrite
    float (*stg)[128] = (float(*)[128])smem;
#pragma unroll
    for (int reg = 0; reg < 4; reg++) {
        int rl = wv * 16 + kg * 4 + reg;
#pragma unroll
        for (int ct = 0; ct < 8; ct++) {
            int c = ct * 16 + cl;
            stg[rl][c] = acc[ct][reg] + hbias[c];
        }
    }
    __syncthreads();
#pragma unroll
    for (int i = 0; i < 4; i++) {
        int idx = tid + i * 256;           // 64 rows x 16 chunks
        int row = idx >> 4, g = idx & 15;
        int gr = blockIdx.x * 64 + row;
        float v[8];
        *(float4*)&v[0] = *(float4*)&stg[row][g * 8];
        *(float4*)&v[4] = *(float4*)&stg[row][g * 8 + 4];
        if (gr < NN) *(uint2*)&H8[(size_t)gr * 128 + g * 8] = fp8x8_enc(v);
    }
}

// ---------------- CSR build: bucket counts -> scan196 -> partition -> fine scatter ----------------
__global__ __launch_bounds__(256) void bucket_count_kernel(const int* __restrict__ edst, int* __restrict__ bucket_cnt) {
    __shared__ int hist[NBUCK];
    int tid = threadIdx.x;
    for (int b = tid; b < NBUCK; b += 256) hist[b] = 0;
    __syncthreads();
    int epb = (NE + gridDim.x - 1) / gridDim.x;
    int e0 = blockIdx.x * epb;
    int e1 = min(e0 + epb, NE);
    for (int e = e0 + tid; e < e1; e += 256) atomicAdd(&hist[edst[e] >> BSH], 1);
    __syncthreads();
    for (int b = tid; b < NBUCK; b += 256) if (hist[b]) atomicAdd(&bucket_cnt[b], hist[b]);
}

__global__ __launch_bounds__(256) void scan196_kernel(const int* __restrict__ bucket_cnt,
                                                      int* __restrict__ bucket_base, int* __restrict__ bcur) {
    __shared__ int sm[256];
    int tid = threadIdx.x;
    int v = (tid < NBUCK) ? bucket_cnt[tid] : 0;
    sm[tid] = v;
    __syncthreads();
    for (int off = 1; off < 256; off <<= 1) {
        int t = (tid >= off) ? sm[tid - off] : 0;
        __syncthreads();
        sm[tid] += t;
        __syncthreads();
    }
    if (tid < NBUCK) {
        int ex = sm[tid] - v;
        bucket_base[tid] = ex;
        bcur[tid] = ex;
    }
    if (tid == NBUCK - 1) bucket_base[NBUCK] = sm[tid];
}

__global__ __launch_bounds__(256) void partition_kernel(const int* __restrict__ esrc, const int* __restrict__ edst,
                                                        int* __restrict__ bcur, int2* __restrict__ ebuf) {
    __shared__ int hist[NBUCK];
    __shared__ int cur[NBUCK];
    int tid = threadIdx.x;
    for (int b = tid; b < NBUCK; b += 256) hist[b] = 0;
    __syncthreads();
    int epb = (NE + gridDim.x - 1) / gridDim.x;
    int e0 = blockIdx.x * epb;
    int e1 = min(e0 + epb, NE);
    for (int e = e0 + tid; e < e1; e += 256)
        atomicAdd(&hist[edst[e] >> BSH], 1);
    __syncthreads();
    for (int b = tid; b < NBUCK; b += 256) {
        int h = hist[b];
        cur[b] = h ? atomicAdd(&bcur[b], h) : 0;
    }
    __syncthreads();
    for (int e = e0 + tid; e < e1; e += 256) {
        int s = esrc[e], d = edst[e];
        int pos = atomicAdd(&cur[d >> BSH], 1);
        ebuf[pos] = make_int2(s, d);
    }
}

// per bucket: LDS deg count + scan -> rowptr; LDS cursors -> csr_src scatter
__global__ __launch_bounds__(256) void fine_scatter_kernel(const int2* __restrict__ ebuf,
                                                           const int* __restrict__ bucket_base,
                                                           int* __restrict__ rowptr, int* __restrict__ csr_src) {
    __shared__ int ldeg[256];
    __shared__ int ssc[256];
    __shared__ int lcur[256];
    int b = blockIdx.x, tid = threadIdx.x;
    int n0 = b << BSH;
    int e0 = bucket_base[b], e1 = bucket_base[b + 1];
    ldeg[tid] = 0;
    __syncthreads();
    for (int e = e0 + tid; e < e1; e += 256) atomicAdd(&ldeg[ebuf[e].y - n0], 1);
    __syncthreads();
    int d = ldeg[tid];
    ssc[tid] = d;
    __syncthreads();
    for (int off = 1; off < 256; off <<= 1) {
        int t = (tid >= off) ? ssc[tid - off] : 0;
        __syncthreads();
        ssc[tid] += t;
        __syncthreads();
    }
    int excl = e0 + ssc[tid] - d;
    int n = n0 + tid;
    if (n < NN) rowptr[n] = excl;
    lcur[tid] = excl;
    if (b == NBUCK - 1 && tid == 0) rowptr[NN] = e1;
    __syncthreads();
    for (int e = e0 + tid; e < e1; e += 256) {
        int2 p = ebuf[e];
        int pos = atomicAdd(&lcur[p.y - n0], 1);
        csr_src[pos] = p.x;
    }
}

// ---------------- GAT layer 1 aggregation: single pass, no max, fp8 H in, bf16 out ----------------
__global__ __launch_bounds__(256) void gat1_agg_kernel(const u8* __restrict__ H8, const float* __restrict__ as1,
                                                       const float* __restrict__ ad1, const int* __restrict__ rowptr,
                                                       const int* __restrict__ csr_src, const float* __restrict__ bias1,
                                                       u16* __restrict__ out) {
    int n = blockIdx.x * 4 + (threadIdx.x >> 6);
    int lane = threadIdx.x & 63;
    int quarter = lane >> 4;   // which edge of the in-flight quad
    int within = lane & 15;    // channel group: [within*8, within*8+8)
    int head = within >> 2;    // head of these channels
    int c8 = within * 8;
    int start = rowptr[n], end = rowptr[n + 1];

    float4 ad4 = *(const float4*)&ad1[n * 4];
    float4 as4 = *(const float4*)&as1[n * 4];
    float ps0 = __expf(lrelu(as4.x + ad4.x));
    float ps1 = __expf(lrelu(as4.y + ad4.y));
    float ps2 = __expf(lrelu(as4.z + ad4.z));
    float ps3 = __expf(lrelu(as4.w + ad4.w));
    float pselfh = (head == 0) ? ps0 : (head == 1) ? ps1 : (head == 2) ? ps2 : ps3;

    float acc[8];
    {   // self-loop contribution (quarter 0 only; folded later)
        uint2 hv = *(const uint2*)&H8[(size_t)n * 128 + c8];
        float h[8];
        fp8x8_dec(hv, h);
        float w = (quarter == 0) ? pselfh : 0.f;
#pragma unroll
        for (int k = 0; k < 8; k++) acc[k] = w * h[k];
    }
    float d0 = 0.f, d1 = 0.f, d2 = 0.f, d3 = 0.f;

    for (int base = start; base < end; base += 64) {
        int i = base + lane;
        int s = 0;
        float p0 = 0.f, p1 = 0.f, p2 = 0.f, p3 = 0.f;
        if (i < end) {
            s = csr_src[i];
            float4 a = *(const float4*)&as1[(size_t)s * 4];
            p0 = __expf(lrelu(a.x + ad4.x));
            p1 = __expf(lrelu(a.y + ad4.y));
            p2 = __expf(lrelu(a.z + ad4.z));
            p3 = __expf(lrelu(a.w + ad4.w));
            d0 += p0; d1 += p1; d2 += p2; d3 += p3;
        }
        int cnt = min(64, end - base);
#pragma unroll 4
        for (int j = 0; j < cnt; j += 4) {
            int jj = j + quarter;
            int s0 = __shfl(s, jj);
            float q0 = __shfl(p0, jj);
            float q1 = __shfl(p1, jj);
            float q2 = __shfl(p2, jj);
            float q3 = __shfl(p3, jj);
            float pp = (head == 0) ? q0 : (head == 1) ? q1 : (head == 2) ? q2 : q3;
            if (jj < cnt) {
                uint2 hv = *(const uint2*)&H8[(size_t)s0 * 128 + c8];
                float h[8];
                fp8x8_dec(hv, h);
#pragma unroll
                for (int k = 0; k < 8; k++) acc[k] += pp * h[k];
            }
        }
    }

#pragma unroll
    for (int off = 1; off < 64; off <<= 1) {
        d0 += __shfl_xor(d0, off);
        d1 += __shfl_xor(d1, off);
        d2 += __shfl_xor(d2, off);
        d3 += __shfl_xor(d3, off);
    }
    float den = ((head == 0) ? d0 : (head == 1) ? d1 : (head == 2) ? d2 : d3) + pselfh;
#pragma unroll
    for (int k = 0; k < 8; k++) {
        acc[k] += __shfl_xor(acc[k], 16);
        acc[k] += __shfl_xor(acc[k], 32);
    }
    if (quarter == 0) {
        float inv = 1.f / den;
        float4 b0 = *(const float4*)&bias1[c8];
        float4 b1 = *(const float4*)&bias1[c8 + 4];
        ushort8 o;
        o[0] = f2bf(fmaxf(acc[0] * inv + b0.x, 0.f));
        o[1] = f2bf(fmaxf(acc[1] * inv + b0.y, 0.f));
        o[2] = f2bf(fmaxf(acc[2] * inv + b0.z, 0.f));
        o[3] = f2bf(fmaxf(acc[3] * inv + b0.w, 0.f));
        o[4] = f2bf(fmaxf(acc[4] * inv + b1.x, 0.f));
        o[5] = f2bf(fmaxf(acc[5] * inv + b1.y, 0.f));
        o[6] = f2bf(fmaxf(acc[6] * inv + b1.z, 0.f));
        o[7] = f2bf(fmaxf(acc[7] * inv + b1.w, 0.f));
        *(ushort8*)&out[(size_t)n * 128 + c8] = o;
    }
}

// ---------------- GEMM2 via MFMA bf16: H2[N,16] = out1b @ W2p + fused as2/ad2 ----------------
__global__ __launch_bounds__(256) void gemm2_mfma_kernel(const u16* __restrict__ Xb, const u16* __restrict__ W2pT,
                                                         const float* __restrict__ hb, const float* __restrict__ atts,
                                                         const float* __restrict__ attd, float* __restrict__ H2,
                                                         float* __restrict__ as_o, float* __restrict__ ad_o) {
    __shared__ u16 wlds[16][136];
    int tid = threadIdx.x;
    {
        int c = tid >> 4, ch = tid & 15;
        *(ushort8*)&wlds[c][ch * 8] = *(const ushort8*)&W2pT[c * 128 + ch * 8];
    }
    int lane = tid & 63, wv = tid >> 6;
    int cl = lane & 15, kg = lane >> 4;
    int row_base = blockIdx.x * 64 + wv * 16;
    int rr = min(row_base + cl, NN - 1);
    __syncthreads();

    f32x4 a = {0.f, 0.f, 0.f, 0.f};
#pragma unroll
    for (int kb = 0; kb < 4; kb++) {
        ushort8 av = *(const ushort8*)&Xb[(size_t)rr * 128 + kb * 32 + kg * 8];
        ushort8 bv = *(const ushort8*)&wlds[cl][kb * 32 + kg * 8];
        a = __builtin_amdgcn_mfma_f32_16x16x32_bf16((short8v)av, (short8v)bv, a, 0, 0, 0);
    }
    float ats = atts[cl], atd = attd[cl], hbc = hb[cl];
#pragma unroll
    for (int reg = 0; reg < 4; reg++) {
        int r = row_base + kg * 4 + reg;
        bool valid = (r < NN);
        float v = a[reg] + hbc;
        if (valid) H2[(size_t)r * 16 + cl] = v;
        float s = v * ats, d = v * atd;
#pragma unroll
        for (int off = 1; off < 16; off <<= 1) {
            s += __shfl_xor(s, off);
            d += __shfl_xor(d, off);
        }
        if (valid) {
            if (cl == 0) as_o[r] = s;
            else if (cl == 1) ad_o[r] = d;
        }
    }
}

// ---------------- GAT layer 2 aggregation: single pass, no max; + bias + GELU ----------------
__global__ __launch_bounds__(256) void gat2_agg_kernel(const float* __restrict__ H2, const float* __restrict__ as2,
                                                       const float* __restrict__ ad2, const int* __restrict__ rowptr,
                                                       const int* __restrict__ csr_src, const float* __restrict__ bias2,
                                                       float* __restrict__ out) {
    int n = blockIdx.x * 4 + (threadIdx.x >> 6);
    int lane = threadIdx.x & 63;
    int quarter = lane >> 4;
    int c = lane & 15;
    int start = rowptr[n], end = rowptr[n + 1];
    float adn = ad2[n], asn = as2[n];
    float pself = __expf(lrelu(asn + adn));

    float acc = (quarter == 0) ? pself * H2[(size_t)n * 16 + c] : 0.f;
    float d = 0.f;

    for (int base = start; base < end; base += 64) {
        int i = base + lane;
        int s = 0;
        float p = 0.f;
        if (i < end) {
            s = csr_src[i];
            p = __expf(lrelu(as2[s] + adn));
            d += p;
        }
        int cnt = min(64, end - base);
#pragma unroll 4
        for (int j = 0; j < cnt; j += 4) {
            int jj = j + quarter;
            int s0 = __shfl(s, jj);
            float q = __shfl(p, jj);
            if (jj < cnt) acc += q * H2[(size_t)s0 * 16 + c];
        }
    }
#pragma unroll
    for (int off = 1; off < 64; off <<= 1) d += __shfl_xor(d, off);
    float den = d + pself;
    acc += __shfl_xor(acc, 16);
    acc += __shfl_xor(acc, 32);

    if (quarter == 0) {
        float xo = acc / den + bias2[c];
        float t = tanhf(0.7978845608028654f * (xo + 0.044715f * xo * xo * xo));
        out[(size_t)n * 16 + c] = 0.5f * xo * (1.f + t);
    }
}

// ---------------- mean pool per graph + log_softmax ----------------
__global__ __launch_bounds__(256) void pool_lsm_kernel(const float* __restrict__ X, const int* __restrict__ batch,
                                                       int nn, float* __restrict__ out) {
    int g = blockIdx.x;
    int tid = threadIdx.x;
    int lo = 0, hi = nn;
    while (lo < hi) { int mid = (lo + hi) >> 1; if (batch[mid] < g) lo = mid + 1; else hi = mid; }
    int s = lo;
    lo = s; hi = nn;
    while (lo < hi) { int mid = (lo + hi) >> 1; if (batch[mid] < g + 1) lo = mid + 1; else hi = mid; }
    int e2 = lo;
    int c = tid & 15, grp = tid >> 4;
    float acc = 0.f;
    for (int r = s + grp; r < e2; r += 16) acc += X[(size_t)r * 16 + c];
    __shared__ float sm[256];
    sm[tid] = acc;
    __syncthreads();
    for (int off = 8; off >= 1; off >>= 1) {
        if (grp < off) sm[tid] += sm[tid + off * 16];
        __syncthreads();
    }
    if (tid < 16) {
        float cnt = (float)(e2 - s);
        float v = sm[tid] / fmaxf(cnt, 1.f);
        float mx = v;
        mx = fmaxf(mx, __shfl_xor(mx, 1));
        mx = fmaxf(mx, __shfl_xor(mx, 2));
        mx = fmaxf(mx, __shfl_xor(mx, 4));
        mx = fmaxf(mx, __shfl_xor(mx, 8));
        float ex = __expf(v - mx);
        float ssum = ex;
        ssum += __shfl_xor(ssum, 1);
        ssum += __shfl_xor(ssum, 2);
        ssum += __shfl_xor(ssum, 4);
        ssum += __shfl_xor(ssum, 8);
        out[g * 16 + tid] = v - mx - __logf(ssum);
    }
}

extern "C" void kernel_launch(void* const* d_in, const int* in_sizes, int n_in,
                              void* d_out, int out_size, void* d_ws, size_t ws_size,
                              hipStream_t stream) {
    const float* x        = (const float*)d_in[0];
    const float* W1       = (const float*)d_in[1];
    const float* att_src1 = (const float*)d_in[2];
    const float* att_dst1 = (const float*)d_in[3];
    const float* bias1    = (const float*)d_in[4];
    const float* W2       = (const float*)d_in[5];
    const float* att_src2 = (const float*)d_in[6];
    const float* att_dst2 = (const float*)d_in[7];
    const float* bias2    = (const float*)d_in[8];
    const float* bn1g     = (const float*)d_in[9];
    const float* bn1b     = (const float*)d_in[10];
    const float* bn2g     = (const float*)d_in[11];
    const float* bn2b     = (const float*)d_in[12];
    const int*   ei       = (const int*)d_in[13];
    const int*   batch    = (const int*)d_in[14];
    float* out = (float*)d_out;

    char* p = (char*)d_ws;
    auto alloc = [&](size_t bytes) -> char* {
        char* r = p;
        p += (bytes + 255) & ~(size_t)255;
        return r;
    };
    float* bnbuf      = (float*)alloc(512 * sizeof(float));     // bn1sum|bn1ss|bn2sum|bn2ss (2048B, 256-aligned)
    int*   bucket_cnt = (int*)alloc(NBUCK * sizeof(int));       // contiguous with bnbuf -> single memset
    int*   bucket_base= (int*)alloc((NBUCK + 1) * sizeof(int));
    int*   bcur       = (int*)alloc(NBUCK * sizeof(int));
    int*   rowptr     = (int*)alloc((NN + 1) * sizeof(int));
    int*   csr_src    = (int*)alloc(NE * sizeof(int));
    int2*  ebuf       = (int2*)alloc((size_t)NE * sizeof(int2));
    u16*   W1pT       = (u16*)alloc(128 * 128 * sizeof(u16));   // bf16 W1 (BN-folded, transposed)
    float* h1bias     = (float*)alloc(128 * sizeof(float));
    u8*    h8         = (u8*)alloc((size_t)NN * 128 * sizeof(u8));     // fp8 H1
    float* as1        = (float*)alloc((size_t)NN * 4 * sizeof(float));
    float* ad1        = (float*)alloc((size_t)NN * 4 * sizeof(float));
    u16*   out1b      = (u16*)alloc((size_t)NN * 128 * sizeof(u16));   // bf16 layer-1 output
    u16*   W2pT       = (u16*)alloc(16 * 128 * sizeof(u16));
    float* h2bias     = (float*)alloc(16 * sizeof(float));
    float* h2         = (float*)alloc((size_t)NN * 16 * sizeof(float));
    float* as2        = (float*)alloc(NN * sizeof(float));
    float* ad2        = (float*)alloc(NN * sizeof(float));
    float* out2g      = (float*)alloc((size_t)NN * 16 * sizeof(float));

    float* bn1sum = bnbuf;
    float* bn1ss  = bnbuf + 128;
    float* bn2sum = bnbuf + 256;
    float* bn2ss  = bnbuf + 384;
    const int* esrc = ei;
    const int* edst = ei + NE;

    // zero: bn stats (2048B) + bucket_cnt (784B) contiguous
    hipMemsetAsync(bnbuf, 0, 512 * sizeof(float) + NBUCK * sizeof(int), stream);

    const float inv_n = 1.f / (float)NN;

    col_stats_kernel<<<256, 256, 0, stream>>>(x, NN, bn1sum, bn1ss);
    bn_prep1_kernel<<<1, 128, 0, stream>>>(bn1sum, bn1ss, bn1g, bn1b, W1, inv_n, W1pT, h1bias);
    gemm1_mfma_kernel<<<(NN + 63) / 64, 256, 0, stream>>>(x, W1pT, h1bias, att_src1, att_dst1, h8, as1, ad1);
    bucket_count_kernel<<<256, 256, 0, stream>>>(edst, bucket_cnt);
    scan196_kernel<<<1, 256, 0, stream>>>(bucket_cnt, bucket_base, bcur);
    partition_kernel<<<256, 256, 0, stream>>>(esrc, edst, bcur, ebuf);
    fine_scatter_kernel<<<NBUCK, 256, 0, stream>>>(ebuf, bucket_base, rowptr, csr_src);
    gat1_agg_kernel<<<NN / 4, 256, 0, stream>>>(h8, as1, ad1, rowptr, csr_src, bias1, out1b);
    col_stats_bf16_kernel<<<256, 256, 0, stream>>>(out1b, NN, bn2sum, bn2ss);
    bn_prep2_kernel<<<1, 128, 0, stream>>>(bn2sum, bn2ss, bn2g, bn2b, W2, inv_n, W2pT, h2bias);
    gemm2_mfma_kernel<<<(NN + 63) / 64, 256, 0, stream>>>(out1b, W2pT, h2bias, att_src2, att_dst2, h2, as2, ad2);
    gat2_agg_kernel<<<NN / 4, 256, 0, stream>>>(h2, as2, ad2, rowptr, csr_src, bias2, out2g);
    pool_lsm_kernel<<<NG, 256, 0, stream>>>(out2g, batch, NN, out);
}